// Round 1
// baseline (399.741 us; speedup 1.0000x reference)
//
#include <hip/hip_runtime.h>
#include <hip/hip_fp16.h>

// Layout: per level, fp16 ROW-PAIR repack R[y][x] = half2(img[y][x], img[min(y+1,S-1)][x]).
// One bilinear quad = one 8-byte load. Zero-padding folded into weights (see sample_level).
//
// This round:
//  1. NT cache hints: level-1 gathers (16.8 MB footprint, ~0 L2 reuse), uv loads and
//     out stores (touch-once streams) are nontemporal -> stop thrashing level-2's
//     4 MB working set out of the per-XCD L2.
//  2. All 4 repacks fused into one launch (5 -> 2 dispatches).
//  3. 2 points/thread: float4 uv load, float2 out store, 8 gathers in flight.

typedef unsigned int u32x2 __attribute__((ext_vector_type(2)));
typedef float f32x2 __attribute__((ext_vector_type(2)));
typedef float f32x4 __attribute__((ext_vector_type(4)));

__global__ __launch_bounds__(256) void repack_all_kernel(
    const float* __restrict__ l1, const float* __restrict__ l2,
    const float* __restrict__ l3, const float* __restrict__ l4,
    __half2* __restrict__ r1, __half2* __restrict__ r2,
    __half2* __restrict__ r3, __half2* __restrict__ r4) {
    const int n1 = 2048 * 2048, n2 = 1024 * 1024, n3 = 512 * 512, n4 = 256 * 256;
    int i = blockIdx.x * 256 + threadIdx.x;
    const float* __restrict__ src;
    __half2* __restrict__ dst;
    int S, logS, j;
    if (i < n1) {
        src = l1; dst = r1; S = 2048; logS = 11; j = i;
    } else if (i < n1 + n2) {
        src = l2; dst = r2; S = 1024; logS = 10; j = i - n1;
    } else if (i < n1 + n2 + n3) {
        src = l3; dst = r3; S = 512; logS = 9; j = i - (n1 + n2);
    } else if (i < n1 + n2 + n3 + n4) {
        src = l4; dst = r4; S = 256; logS = 8; j = i - (n1 + n2 + n3);
    } else {
        return;
    }
    int y = j >> logS;
    float a = src[j];
    float b = src[(y < S - 1) ? (j + S) : j];
    dst[j] = __halves2half2(__float2half(a), __float2half(b));
}

template <bool NT>
__device__ __forceinline__ float sample_level(const __half2* __restrict__ R,
                                              const int S, const float gx,
                                              const float gy) {
    const float halfS = 0.5f * (float)S;
    float x = (gx + 1.0f) * halfS - 0.5f;
    float y = (gy + 1.0f) * halfS - 0.5f;
    float xf = floorf(x), yf = floorf(y);
    float wx = x - xf, wy = y - yf;
    int x0 = (int)xf, y0 = (int)yf;

    int yc = min(max(y0, 0), S - 1);
    float wa = (y0 >= 0) ? (1.0f - wy) : wy;
    if (y0 < -1 || y0 >= S) wa = 0.0f;  // defensive (outside expected domain)
    float wb = (y0 >= 0 && y0 < S - 1) ? wy : 0.0f;

    int xb = min(max(x0, 0), S - 2);
    bool xin = (x0 >= 0) && (x0 <= S - 2);
    float wxa = xin ? (1.0f - wx) : ((x0 == -1) ? wx : 0.0f);
    float wxb = xin ? wx : ((x0 == S - 1) ? (1.0f - wx) : 0.0f);

    const char* p = (const char*)(R + (size_t)yc * (size_t)S + xb);
    u32x2 q;
    if (NT) {
        // evict-first in L1/L2: this level's lines have ~zero short-term reuse.
        // (address is 4-B aligned; gfx950 global dwordx2 tolerates align-4, same
        // instruction the memcpy path emits.)
        q = __builtin_nontemporal_load((const u32x2*)p);
    } else {
        __builtin_memcpy(&q, p, 8);
    }
    unsigned int qa = q.x, qb = q.y;
    __half2 ca, cb;
    __builtin_memcpy(&ca, &qa, 4);  // (img[yc][xb],   img[yc+1][xb])
    __builtin_memcpy(&cb, &qb, 4);  // (img[yc][xb+1], img[yc+1][xb+1])
    float2 fa = __half22float2(ca);
    float2 fb = __half22float2(cb);
    float cola = fmaf(wa, fa.x, wb * fa.y);
    float colb = fmaf(wa, fb.x, wb * fb.y);
    return fmaf(wxa, cola, wxb * colb);
}

__device__ __forceinline__ float sample_point(const __half2* __restrict__ r1,
                                              const __half2* __restrict__ r2,
                                              const __half2* __restrict__ r3,
                                              const __half2* __restrict__ r4,
                                              float ux, float uy) {
    float gx = ux * 2.0f - 1.0f;
    float gy = uy * 2.0f - 1.0f;
    float acc = sample_level<true>(r1, 2048, gx, gy);   // 16.8 MB: NT
    acc += sample_level<false>(r2, 1024, gx, gy);       // 4 MB: keep cached
    acc += sample_level<false>(r3, 512, gx, gy);
    acc += sample_level<false>(r4, 256, gx, gy);
    return acc;
}

__global__ __launch_bounds__(256) void lappyr_sample_kernel(
    const float2* __restrict__ uv, const __half2* __restrict__ r1,
    const __half2* __restrict__ r2, const __half2* __restrict__ r3,
    const __half2* __restrict__ r4, float* __restrict__ out, int n) {
    int i = blockIdx.x * 256 + threadIdx.x;
    int p0 = i * 2;
    if (p0 >= n) return;
    if (p0 + 1 < n) {
        // 2 points/thread: one 16-B NT uv load, 8 gathers in flight, one 8-B NT store.
        f32x4 u = __builtin_nontemporal_load((const f32x4*)uv + i);
        float a0 = sample_point(r1, r2, r3, r4, u.x, u.y);
        float a1 = sample_point(r1, r2, r3, r4, u.z, u.w);
        f32x2 res;
        res.x = a0;
        res.y = a1;
        __builtin_nontemporal_store(res, (f32x2*)(out + p0));
    } else {
        float2 p = uv[p0];
        out[p0] = sample_point(r1, r2, r3, r4, p.x, p.y);
    }
}

// ---- fallback (ws too small): direct f32 sampling, known-good baseline ----
__device__ __forceinline__ float bilin_f32(const float* __restrict__ img,
                                           const int S, const float gx,
                                           const float gy) {
    const float halfS = 0.5f * (float)S;
    float x = (gx + 1.0f) * halfS - 0.5f;
    float y = (gy + 1.0f) * halfS - 0.5f;
    float xf = floorf(x), yf = floorf(y);
    float wx = x - xf, wy = y - yf;
    int x0 = (int)xf, y0 = (int)yf, x1 = x0 + 1, y1 = y0 + 1;
    float ex0 = (x0 >= 0 && x0 < S) ? (1.0f - wx) : 0.0f;
    float ex1 = (x1 >= 0 && x1 < S) ? wx : 0.0f;
    float ey0 = (y0 >= 0 && y0 < S) ? (1.0f - wy) : 0.0f;
    float ey1 = (y1 >= 0 && y1 < S) ? wy : 0.0f;
    int xc0 = min(max(x0, 0), S - 1), xc1 = min(max(x1, 0), S - 1);
    int yc0 = min(max(y0, 0), S - 1), yc1 = min(max(y1, 0), S - 1);
    const float* r0 = img + (size_t)yc0 * S;
    const float* r1 = img + (size_t)yc1 * S;
    return ey0 * fmaf(ex0, r0[xc0], ex1 * r0[xc1]) +
           ey1 * fmaf(ex0, r1[xc0], ex1 * r1[xc1]);
}

__global__ __launch_bounds__(256) void lappyr_f32_kernel(
    const float2* __restrict__ uv, const float* __restrict__ l1,
    const float* __restrict__ l2, const float* __restrict__ l3,
    const float* __restrict__ l4, float* __restrict__ out, int n) {
    int i = blockIdx.x * blockDim.x + threadIdx.x;
    if (i >= n) return;
    float2 p = uv[i];
    float gx = p.x * 2.0f - 1.0f;
    float gy = p.y * 2.0f - 1.0f;
    float acc = bilin_f32(l1, 2048, gx, gy);
    acc += bilin_f32(l2, 1024, gx, gy);
    acc += bilin_f32(l3, 512, gx, gy);
    acc += bilin_f32(l4, 256, gx, gy);
    out[i] = acc;
}

extern "C" void kernel_launch(void* const* d_in, const int* in_sizes, int n_in,
                              void* d_out, int out_size, void* d_ws, size_t ws_size,
                              hipStream_t stream) {
    const float2* uv = (const float2*)d_in[0];
    const float* l1 = (const float*)d_in[1];
    const float* l2 = (const float*)d_in[2];
    const float* l3 = (const float*)d_in[3];
    const float* l4 = (const float*)d_in[4];
    float* out = (float*)d_out;
    int n = out_size;

    const size_t n1 = 2048u * 2048u, n2 = 1024u * 1024u, n3 = 512u * 512u,
                 n4 = 256u * 256u;
    const size_t need = (n1 + n2 + n3 + n4) * sizeof(__half2);  // ~21.25 MiB

    if (ws_size >= need) {
        __half2* r1 = (__half2*)d_ws;
        __half2* r2 = r1 + n1;
        __half2* r3 = r2 + n2;
        __half2* r4 = r3 + n3;
        const size_t ntot = n1 + n2 + n3 + n4;
        repack_all_kernel<<<(int)((ntot + 255) / 256), 256, 0, stream>>>(
            l1, l2, l3, l4, r1, r2, r3, r4);
        int nh = (n + 1) / 2;
        lappyr_sample_kernel<<<(nh + 255) / 256, 256, 0, stream>>>(uv, r1, r2, r3,
                                                                   r4, out, n);
    } else {
        lappyr_f32_kernel<<<(n + 255) / 256, 256, 0, stream>>>(uv, l1, l2, l3, l4,
                                                               out, n);
    }
}